// Round 13
// baseline (44.887 us; speedup 1.0000x reference)
//
#include <hip/hip_runtime.h>
#include <math.h>

#define DIM   100
#define NV    64
#define BS    512
#define MAXCH 1792          // multiple of 256; >= 128 combos * 13 chunks
#define SMW   108           // padded mask row stride (bytes)
#define SMH   103           // padded mask rows
#define MSZ   (SMH * SMW)   // one padded mask slice (11124 B)

// ---------------------------------------------------------------------------
// One 512-THREAD block per (batch, direction-PAIR). DIRECTIONS = [x,x,y,y]:
// slices (4b+0,4b+1) share axis x, (4b+2,4b+3) share y -> edges, sign, bbox,
// exact last-valid-step T, K and chunk table are IDENTICAL within a pair;
// only the mask differs. Block stages BOTH masks (clamp-padded u8 103x108,
// R10-proven: bilinear = 4 ds_read_u8 at fixed immediate offsets, exact
// clip() semantics) and runs ONE fused main loop: shared t/weights/address
// per sample + two gathers + two FMAs (R12-proven numerics, absmax 4.88e-4).
// R12's failure was occupancy (256-thread blocks -> 16 waves/CU). Fix:
// 512 threads, __launch_bounds__(512,8) -> 4 blocks/CU x 8 waves = 32
// waves/CU (full), LDS 4 x ~30 KB = 121 <= 160 KB, grid 1024 = 4*256
// exactly co-resident, VGPR cap 64 (R12 used 44).
// ---------------------------------------------------------------------------
template<bool AX>
__device__ __forceinline__ void mainloop(
    const unsigned char* sm, const float4* prmA, const float4* prmB,
    const unsigned short* chunkTab, int totE, int tid,
    float& acc0o, float& acc1o) {
  const int grp = tid >> 5;                // 0..15
  const int sub = (tid >> 3) & 3;          // 0..3
  const int st  = tid & 7;                 // kept-sample index within chunk
  const int base0 = grp * 16 + sub * 4;
  float acc0 = 0.0f, acc1 = 0.0f;

  for (int i = 0; i * 256 < totE; ++i) {
    const ushort4 ent = *reinterpret_cast<const ushort4*>(
        &chunkTab[i * 256 + base0]);       // ds_read_b64 entry quad

    // p = {x0,y0,vx,vy}; q = {shw, Kf, B, A'}
    #define SAMPLE(e) {                                                    \
      const int c = (e) >> 4;                                              \
      const float kf = (float)((((e) & 15) << 3) | st);                    \
      const float4 p = prmA[c];                                            \
      const float4 q = prmB[c];                                            \
      const float vu = AX ? p.z : p.w;                                     \
      const float u0 = AX ? p.x : p.y;                                     \
      const float fu0 = floorf(u0);                                        \
      const float ck = fu0 + __builtin_copysignf(kf, vu);                  \
      const float te = ceilf(fmaf(kf, q.z, q.w));                          \
      const float u1 = __fadd_rn(__fmul_rn(te, vu), u0);                   \
      float t = (floorf(u1) == ck) ? te : (te + 1.0f);                     \
      t = fmaxf(t, 0.0f);                                                  \
      const float xs = __fadd_rn(__fmul_rn(t, p.z), p.x);                  \
      const float ys = __fadd_rn(__fmul_rn(t, p.w), p.y);                  \
      const float X0 = floorf(xs), Y0 = floorf(ys);                        \
      const float wx1 = xs - X0, wy1 = ys - Y0;                            \
      const float wx0 = 1.0f - wx1, wy0 = 1.0f - wy1;                      \
      const int ix = max(min((int)X0, 100), -1);                           \
      const int iy = max(min((int)Y0, 100), -1);                           \
      const int a = iy * SMW + ix;                                         \
      const float g00a = (float)sm[a + (SMW + 4)];                         \
      const float g10a = (float)sm[a + (SMW + 5)];                         \
      const float g01a = (float)sm[a + (2 * SMW + 4)];                     \
      const float g11a = (float)sm[a + (2 * SMW + 5)];                     \
      const float g00b = (float)sm[a + (MSZ + SMW + 4)];                   \
      const float g10b = (float)sm[a + (MSZ + SMW + 5)];                   \
      const float g01b = (float)sm[a + (MSZ + 2 * SMW + 4)];               \
      const float g11b = (float)sm[a + (MSZ + 2 * SMW + 5)];               \
      const float topa = fmaf(wx1, g10a, wx0 * g00a);                      \
      const float bota = fmaf(wx1, g11a, wx0 * g01a);                      \
      const float vala = fmaf(wy1, bota, wy0 * topa);                      \
      const float topb = fmaf(wx1, g10b, wx0 * g00b);                      \
      const float botb = fmaf(wx1, g11b, wx0 * g01b);                      \
      const float valb = fmaf(wy1, botb, wy0 * topb);                      \
      const float w = (kf <= q.y) ? q.x : 0.0f;                            \
      acc0 = fmaf(w, vala, acc0);                                          \
      acc1 = fmaf(w, valb, acc1);                                          \
    }
    SAMPLE(ent.x); SAMPLE(ent.y); SAMPLE(ent.z); SAMPLE(ent.w);
    #undef SAMPLE
  }
  acc0o = acc0; acc1o = acc1;
}

__global__ __launch_bounds__(512, 8) void diffiou_intersect(
    const float* __restrict__ poly, const float* __restrict__ gt_mask,
    float* __restrict__ ws) {
  __shared__ unsigned char sm[2 * MSZ];          // 22248 B, two padded masks
  __shared__ float4 prmA[128];                   // 2048 B: x0,y0,vx,vy
  __shared__ float4 prmB[128];                   // 2048 B: shw,Kf,B,A'
  __shared__ unsigned short chunkTab[MAXCH];     // 3584 B
  __shared__ int   wsum[2];
  __shared__ int   totalChunks;
  __shared__ float red[8][2];

  const int g   = blockIdx.x;              // 0..1023
  const int b   = g >> 1;
  const int mb  = (g & 1) * 2;             // 0 -> slices {0,1}, 1 -> {2,3}
  const bool ax = (mb == 0);               // DIRECTIONS = x,x,y,y
  const int tid = threadIdx.x;

  // ---- phase 1: stage BOTH clamp-padded u8 masks ----
  #pragma unroll
  for (int s = 0; s < 2; ++s) {
    const float* src = gt_mask + (size_t)(b * 4 + mb + s) * (DIM * DIM);
    unsigned char* dst = sm + s * MSZ;
    for (int j = tid; j < SMH * 25; j += 512) {
      const int r = j / 25;                // 0..102
      const int q = j - r * 25;            // 0..24
      const int sr = min(max(r - 1, 0), DIM - 1);
      const float4 v = *reinterpret_cast<const float4*>(&src[sr * DIM + 4 * q]);
      const unsigned int c0 = (unsigned int)__float2int_rn(v.x * 255.0f);
      const unsigned int c1 = (unsigned int)__float2int_rn(v.y * 255.0f);
      const unsigned int c2 = (unsigned int)__float2int_rn(v.z * 255.0f);
      const unsigned int c3 = (unsigned int)__float2int_rn(v.w * 255.0f);
      *reinterpret_cast<unsigned int*>(&dst[r * SMW + 4 + 4 * q]) =
          c0 | (c1 << 8) | (c2 << 16) | (c3 << 24);   // 4B-aligned
    }
    for (int r = tid; r < SMH; r += 512) { // border duplicates
      const int sr = min(max(r - 1, 0), DIM - 1);
      const unsigned char e0 =
          (unsigned char)__float2int_rn(src[sr * DIM + 0] * 255.0f);
      const unsigned char e9 =
          (unsigned char)__float2int_rn(src[sr * DIM + DIM - 1] * 255.0f);
      dst[r * SMW + 3] = e0;
      dst[r * SMW + 104] = e9;
      dst[r * SMW + 105] = e9;
    }
  }
  for (int j = tid; j < MAXCH; j += 512) chunkTab[j] = 15;  // sentinel

  // ---- per-combo setup (shared by both slices of the pair) ----
  int ncv = 0;
  if (tid < 128) {
    const int e  = tid >> 1;
    const int fb = tid & 1;
    const float* pb = poly + (size_t)b * NV * 2;
    const float ex0 = pb[e * 2 + 0], ey0 = pb[e * 2 + 1];
    const int   en  = (e + 1) & (NV - 1);
    const float ex1 = pb[en * 2 + 0], ey1 = pb[en * 2 + 1];
    const float sign = (ax ? (ex1 > ex0) : (ey1 > ey0)) ? 1.0f : -1.0f;
    const float x0 = fb ? ex1 : ex0, y0 = fb ? ey1 : ey0;
    const float x1 = fb ? ex0 : ex1, y1 = fb ? ey0 : ey1;
    float vx = (x1 - x0) + 1e-6f;
    float vy = (y1 - y0) + 1e-6f;
    const float n = __fsqrt_rn(__fadd_rn(__fmul_rn(vx, vx), __fmul_rn(vy, vy)));
    vx = __fdiv_rn(vx, n);
    vy = __fdiv_rn(vy, n);
    // bbox + tolerances; u-bound [0,99] folded into the axis coord (exact)
    float xlo = fminf(x0, x1) - 0.001f, xhi = fmaxf(x0, x1) + 0.001f;
    float ylo = fminf(y0, y1) - 0.001f, yhi = fmaxf(y0, y1) + 0.001f;
    if (ax) { xlo = fmaxf(xlo, 0.0f); xhi = fminf(xhi, (float)(DIM - 1)); }
    else    { ylo = fmaxf(ylo, 0.0f); yhi = fminf(yhi, (float)(DIM - 1)); }

    #define VALID_AT(tt, out_) {                                  \
      const float tf_ = (float)(tt);                              \
      const float xs_ = __fadd_rn(__fmul_rn(tf_, vx), x0);        \
      const float ys_ = __fadd_rn(__fmul_rn(tf_, vy), y0);        \
      out_ = (xs_ <= xhi) && (xs_ >= xlo) &&                      \
             (ys_ <= yhi) && (ys_ >= ylo);                        \
    }
    int T;
    bool v200; VALID_AT(200, v200);
    if (v200) { T = 200; }
    else {
      int lo = 0, hi = 200;
      #pragma unroll
      for (int it = 0; it < 8; ++it) {
        const int mid = (lo + hi) >> 1;
        bool vm; VALID_AT(mid, vm);
        if (vm) lo = mid; else hi = mid;
      }
      T = lo;
    }
    #undef VALID_AT

    const float vu  = ax ? vx : vy;
    const float u0  = ax ? x0 : y0;
    const float fu0 = floorf(u0);
    const float uT  = __fadd_rn(__fmul_rn((float)T, vu), u0);
    int K = abs((int)floorf(uT) - (int)fu0);
    K = min(K, 99);
    const float B = __fdiv_rn(1.0f, fabsf(vu));
    const float D = (vu > 0.0f) ? (fu0 - u0) : (u0 - fu0 - 1.0f);
    prmA[tid] = make_float4(x0, y0, vx, vy);
    prmB[tid] = make_float4(sign * (0.5f / 255.0f), (float)K,
                            B, fmaf(D, B, -0.005f));
    ncv = (K >> 3) + 1;                    // 8-kept chunks, <= 13
  }

  // ---- prefix scan (waves 0-1) + scatter chunk table ----
  int v = ncv;
  #pragma unroll
  for (int i = 1; i < 64; i <<= 1) {
    const int w = __shfl_up(v, i, 64);
    if ((tid & 63) >= i) v += w;
  }
  if (((tid & 63) == 63) && (tid < 128)) wsum[tid >> 6] = v;
  __syncthreads();
  if ((tid >= 64) && (tid < 128)) v += wsum[0];
  if (tid < 128) {
    const int start = v - ncv;
    for (int k = 0; k < ncv; ++k)
      chunkTab[start + k] = (unsigned short)((tid << 4) | k);
    if (tid == 127) totalChunks = v;
  }
  __syncthreads();

  const int totE = totalChunks;
  float acc0, acc1;
  if (ax) mainloop<true >(sm, prmA, prmB, chunkTab, totE, tid, acc0, acc1);
  else    mainloop<false>(sm, prmA, prmB, chunkTab, totE, tid, acc0, acc1);

  // ---- block reduce (8 waves), both accumulators ----
  #pragma unroll
  for (int o = 32; o > 0; o >>= 1) {
    acc0 += __shfl_xor(acc0, o, 64);
    acc1 += __shfl_xor(acc1, o, 64);
  }
  if ((tid & 63) == 0) { red[tid >> 6][0] = acc0; red[tid >> 6][1] = acc1; }
  __syncthreads();
  if (tid == 0) {
    float s0 = 0.0f, s1 = 0.0f;
    #pragma unroll
    for (int w = 0; w < 8; ++w) { s0 += red[w][0]; s1 += red[w][1]; }
    ws[b * 4 + mb + 0] = fabsf(s0);
    ws[b * 4 + mb + 1] = fabsf(s1);
  }
}

// ---------------------------------------------------------------------------
// Kernel 2: per-batch areas + final IoU. One wave per batch.
// ---------------------------------------------------------------------------
__device__ __forceinline__ float wave_area(const float* P, int b, int v) {
  const float x0 = P[(size_t)(b * NV + v) * 2 + 0];
  const float y0 = P[(size_t)(b * NV + v) * 2 + 1];
  const int vn = (v + 1) & (NV - 1);
  const float x1 = P[(size_t)(b * NV + vn) * 2 + 0];
  const float y1 = P[(size_t)(b * NV + vn) * 2 + 1];
  float ym = y0;
  #pragma unroll
  for (int o = 32; o > 0; o >>= 1) ym = fmaxf(ym, __shfl_xor(ym, o, 64));
  float term = (x1 - x0) * (ym - (y1 + y0) * 0.5f);
  #pragma unroll
  for (int o = 32; o > 0; o >>= 1) term += __shfl_xor(term, o, 64);
  return fabsf(term);
}

__global__ __launch_bounds__(64) void diffiou_finalize(
    const float* __restrict__ poly, const float* __restrict__ gt,
    const float* __restrict__ ws, float* __restrict__ out) {
  const int b = blockIdx.x;
  const int v = threadIdx.x;
  const float pa = wave_area(poly, b, v);
  const float ga = wave_area(gt, b, v);
  if (v == 0) {
    const float ia = 0.25f * (ws[b * 4 + 0] + ws[b * 4 + 1] +
                              ws[b * 4 + 2] + ws[b * 4 + 3]);
    out[b] = ia / (pa + ga - ia);
  }
}

// ---------------------------------------------------------------------------
extern "C" void kernel_launch(void* const* d_in, const int* in_sizes, int n_in,
                              void* d_out, int out_size, void* d_ws, size_t ws_size,
                              hipStream_t stream) {
  const float* poly    = (const float*)d_in[0];
  const float* gt      = (const float*)d_in[1];
  const float* gt_mask = (const float*)d_in[2];
  float* out = (float*)d_out;
  float* ws  = (float*)d_ws;   // 2048 floats: |s| per (batch, direction)

  hipLaunchKernelGGL(diffiou_intersect, dim3(BS * 2), dim3(512), 0, stream,
                     poly, gt_mask, ws);
  hipLaunchKernelGGL(diffiou_finalize, dim3(BS), dim3(64), 0, stream,
                     poly, gt, ws, out);
}

// Round 14
// 35.670 us; speedup vs baseline: 1.2584x; 1.2584x over previous
//
#include <hip/hip_runtime.h>
#include <math.h>

#define DIM   100
#define NV    64
#define BS    512
#define MAXCH 1664          // 128 combos * 13 chunks max, multiple of 128
#define SMW   108           // padded mask row stride (bytes)
#define SMH   103           // padded mask rows
#define SHWC  (0.5f / 255.0f)

// ---------------------------------------------------------------------------
// One 256-thread block per (batch, direction m) — the R10 structure (proven
// best: 8 blocks/CU, 2048-block grid fully co-resident, 32 waves/CU).
// Mask staged as u8 in the CLAMP-PADDED 103x108 layout (bilinear = 4
// ds_read_u8 at fixed immediate offsets, exact clip() semantics). Kept-sample
// direct enumeration (R7-R10): per combo binary-search exact last valid step
// T (bit-exact float exprs), K = cells crossed; per sample t = ceil((k+D)*
// rcp(|vu|) - 5e-3) + one-step fixup vs bit-exact floor(u(t)).
// CHANGE vs R10: prmB (b128/sample) replaced by meta (b32/sample) =
// sign*(K+0.5); B and D recomputed in-loop (R11-verified numerics, absmax
// 4.88e-4 identical). Cuts LDS traffic/sample ~20% at +7 VALU/sample.
// LDS ~17.1 KB -> 8 blocks/CU.
// ---------------------------------------------------------------------------
template<bool AX>
__device__ __forceinline__ float mainloop(
    const unsigned char* sm, const float4* prmA, const float* meta,
    const unsigned short* chunkTab, int totE, int tid) {
  const int grp = tid >> 5;                // 0..7
  const int sub = (tid >> 3) & 3;          // 0..3
  const int st  = tid & 7;                 // kept-sample index within chunk
  const int base0 = grp * 16 + sub * 4;
  float acc = 0.0f;

  for (int i = 0; i * 128 < totE; ++i) {
    const ushort4 ent = *reinterpret_cast<const ushort4*>(
        &chunkTab[i * 128 + base0]);       // one ds_read_b64 per 256 samples

    #define SAMPLE(e) {                                                    \
      const int c = (e) >> 4;                                              \
      const float kf = (float)((((e) & 15) << 3) | st);                    \
      const float4 p = prmA[c];            /* ds_read_b128 */              \
      const float mt = meta[c];            /* ds_read_b32  */              \
      const float vu = AX ? p.z : p.w;                                     \
      const float u0 = AX ? p.x : p.y;                                     \
      const float fu0 = floorf(u0);                                        \
      const float Bv = __builtin_amdgcn_rcpf(fabsf(vu));                   \
      const float D  = (vu > 0.0f) ? (fu0 - u0) : (u0 - fu0 - 1.0f);       \
      const float te = ceilf((kf + D) * Bv - 0.005f);                      \
      const float ck = fu0 + __builtin_copysignf(kf, vu);                  \
      const float u1 = __fadd_rn(__fmul_rn(te, vu), u0);                   \
      float t = (floorf(u1) == ck) ? te : (te + 1.0f);                     \
      t = fmaxf(t, 0.0f);                                                  \
      const float xs = __fadd_rn(__fmul_rn(t, p.z), p.x);                  \
      const float ys = __fadd_rn(__fmul_rn(t, p.w), p.y);                  \
      const float X0 = floorf(xs), Y0 = floorf(ys);                        \
      const float wx1 = xs - X0, wy1 = ys - Y0;                            \
      const float wx0 = 1.0f - wx1, wy0 = 1.0f - wy1;                      \
      const int ix = max(min((int)X0, 100), -1);                           \
      const int iy = max(min((int)Y0, 100), -1);                           \
      const int a = iy * SMW + ix;                                         \
      const float g00 = (float)sm[a + (SMW + 4)];                          \
      const float g10 = (float)sm[a + (SMW + 5)];                          \
      const float g01 = (float)sm[a + (2 * SMW + 4)];                      \
      const float g11 = (float)sm[a + (2 * SMW + 5)];                      \
      const float top = fmaf(wx1, g10, wx0 * g00);                         \
      const float bot = fmaf(wx1, g11, wx0 * g01);                         \
      const float val = fmaf(wy1, bot, wy0 * top);                         \
      const float w = (kf < fabsf(mt)) ? __builtin_copysignf(SHWC, mt)     \
                                       : 0.0f;                             \
      acc = fmaf(w, val, acc);                                             \
    }
    SAMPLE(ent.x); SAMPLE(ent.y); SAMPLE(ent.z); SAMPLE(ent.w);
    #undef SAMPLE
  }
  return acc;
}

__global__ __launch_bounds__(256, 8) void diffiou_intersect(
    const float* __restrict__ poly, const float* __restrict__ gt_mask,
    float* __restrict__ ws) {
  __shared__ unsigned char sm[SMH * SMW];        // 11124 B, clamp-padded
  __shared__ float4 prmA[128];                   // 2048 B: x0,y0,vx,vy
  __shared__ float  meta[128];                   // 512 B: sign*(K+0.5)
  __shared__ unsigned short chunkTab[MAXCH];     // 3328 B
  __shared__ int   wsum[2];
  __shared__ int   totalChunks;
  __shared__ float red[4];

  const int bid = blockIdx.x;
  const int b   = bid >> 2;
  const int m   = bid & 3;
  const bool ax = (m < 2);                 // DIRECTIONS = x,x,y,y
  const int tid = threadIdx.x;

  // ---- phase 1: stage clamp-padded u8 mask ----
  {
    const float* src = gt_mask + (size_t)(b * 4 + m) * (DIM * DIM);
    for (int j = tid; j < SMH * 25; j += 256) {
      const int r = j / 25;                // 0..102
      const int g = j - r * 25;            // 0..24
      const int sr = min(max(r - 1, 0), DIM - 1);
      const float4 v = *reinterpret_cast<const float4*>(&src[sr * DIM + 4 * g]);
      const unsigned int c0 = (unsigned int)__float2int_rn(v.x * 255.0f);
      const unsigned int c1 = (unsigned int)__float2int_rn(v.y * 255.0f);
      const unsigned int c2 = (unsigned int)__float2int_rn(v.z * 255.0f);
      const unsigned int c3 = (unsigned int)__float2int_rn(v.w * 255.0f);
      *reinterpret_cast<unsigned int*>(&sm[r * SMW + 4 + 4 * g]) =
          c0 | (c1 << 8) | (c2 << 16) | (c3 << 24);   // 4B-aligned
    }
    for (int r = tid; r < SMH; r += 256) { // border duplicates
      const int sr = min(max(r - 1, 0), DIM - 1);
      const unsigned char e0 =
          (unsigned char)__float2int_rn(src[sr * DIM + 0] * 255.0f);
      const unsigned char e9 =
          (unsigned char)__float2int_rn(src[sr * DIM + DIM - 1] * 255.0f);
      sm[r * SMW + 3] = e0;
      sm[r * SMW + 104] = e9;
      sm[r * SMW + 105] = e9;
    }
    for (int j = tid; j < MAXCH; j += 256) chunkTab[j] = 15;  // sentinel
  }

  // ---- per-combo setup ----
  int ncv = 0;
  if (tid < 128) {
    const int e  = tid >> 1;
    const int fb = tid & 1;
    const float* pb = poly + (size_t)b * NV * 2;
    const float ex0 = pb[e * 2 + 0], ey0 = pb[e * 2 + 1];
    const int   en  = (e + 1) & (NV - 1);
    const float ex1 = pb[en * 2 + 0], ey1 = pb[en * 2 + 1];
    const float sign = (ax ? (ex1 > ex0) : (ey1 > ey0)) ? 1.0f : -1.0f;
    const float x0 = fb ? ex1 : ex0, y0 = fb ? ey1 : ey0;
    const float x1 = fb ? ex0 : ex1, y1 = fb ? ey0 : ey1;
    float vx = (x1 - x0) + 1e-6f;
    float vy = (y1 - y0) + 1e-6f;
    const float n = __fsqrt_rn(__fadd_rn(__fmul_rn(vx, vx), __fmul_rn(vy, vy)));
    vx = __fdiv_rn(vx, n);
    vy = __fdiv_rn(vy, n);
    // bbox + tolerances; u-bound [0,99] folded into the axis coord (exact)
    float xlo = fminf(x0, x1) - 0.001f, xhi = fmaxf(x0, x1) + 0.001f;
    float ylo = fminf(y0, y1) - 0.001f, yhi = fmaxf(y0, y1) + 0.001f;
    if (ax) { xlo = fmaxf(xlo, 0.0f); xhi = fminf(xhi, (float)(DIM - 1)); }
    else    { ylo = fmaxf(ylo, 0.0f); yhi = fminf(yhi, (float)(DIM - 1)); }

    #define VALID_AT(tt, out_) {                                  \
      const float tf_ = (float)(tt);                              \
      const float xs_ = __fadd_rn(__fmul_rn(tf_, vx), x0);        \
      const float ys_ = __fadd_rn(__fmul_rn(tf_, vy), y0);        \
      out_ = (xs_ <= xhi) && (xs_ >= xlo) &&                      \
             (ys_ <= yhi) && (ys_ >= ylo);                        \
    }
    int T;
    bool v200; VALID_AT(200, v200);
    if (v200) { T = 200; }
    else {
      int lo = 0, hi = 200;
      #pragma unroll
      for (int it = 0; it < 8; ++it) {
        const int mid = (lo + hi) >> 1;
        bool vm; VALID_AT(mid, vm);
        if (vm) lo = mid; else hi = mid;
      }
      T = lo;
    }
    #undef VALID_AT

    const float vu  = ax ? vx : vy;
    const float u0  = ax ? x0 : y0;
    const float fu0 = floorf(u0);
    const float uT  = __fadd_rn(__fmul_rn((float)T, vu), u0);
    int K = abs((int)floorf(uT) - (int)fu0);
    K = min(K, 99);
    prmA[tid] = make_float4(x0, y0, vx, vy);
    meta[tid] = sign * ((float)K + 0.5f);
    ncv = (K >> 3) + 1;                    // 8-kept chunks, <= 13
  }

  // ---- prefix scan (2 waves) + scatter chunk table ----
  int v = ncv;
  #pragma unroll
  for (int i = 1; i < 64; i <<= 1) {
    const int w = __shfl_up(v, i, 64);
    if ((tid & 63) >= i) v += w;
  }
  if (((tid & 63) == 63) && (tid < 128)) wsum[tid >> 6] = v;
  __syncthreads();
  if ((tid >= 64) && (tid < 128)) v += wsum[0];
  if (tid < 128) {
    const int start = v - ncv;
    for (int k = 0; k < ncv; ++k)
      chunkTab[start + k] = (unsigned short)((tid << 4) | k);
    if (tid == 127) totalChunks = v;
  }
  __syncthreads();

  const int totE = totalChunks;
  const float acc = ax ? mainloop<true >(sm, prmA, meta, chunkTab, totE, tid)
                       : mainloop<false>(sm, prmA, meta, chunkTab, totE, tid);

  // ---- block reduce (4 waves) ----
  float a = acc;
  #pragma unroll
  for (int o = 32; o > 0; o >>= 1) a += __shfl_xor(a, o, 64);
  if ((tid & 63) == 0) red[tid >> 6] = a;
  __syncthreads();
  if (tid == 0) {
    const float s = red[0] + red[1] + red[2] + red[3];
    ws[bid] = fabsf(s);
  }
}

// ---------------------------------------------------------------------------
// Kernel 2: per-batch areas + final IoU. One wave per batch.
// ---------------------------------------------------------------------------
__device__ __forceinline__ float wave_area(const float* P, int b, int v) {
  const float x0 = P[(size_t)(b * NV + v) * 2 + 0];
  const float y0 = P[(size_t)(b * NV + v) * 2 + 1];
  const int vn = (v + 1) & (NV - 1);
  const float x1 = P[(size_t)(b * NV + vn) * 2 + 0];
  const float y1 = P[(size_t)(b * NV + vn) * 2 + 1];
  float ym = y0;
  #pragma unroll
  for (int o = 32; o > 0; o >>= 1) ym = fmaxf(ym, __shfl_xor(ym, o, 64));
  float term = (x1 - x0) * (ym - (y1 + y0) * 0.5f);
  #pragma unroll
  for (int o = 32; o > 0; o >>= 1) term += __shfl_xor(term, o, 64);
  return fabsf(term);
}

__global__ __launch_bounds__(64) void diffiou_finalize(
    const float* __restrict__ poly, const float* __restrict__ gt,
    const float* __restrict__ ws, float* __restrict__ out) {
  const int b = blockIdx.x;
  const int v = threadIdx.x;
  const float pa = wave_area(poly, b, v);
  const float ga = wave_area(gt, b, v);
  if (v == 0) {
    const float ia = 0.25f * (ws[b * 4 + 0] + ws[b * 4 + 1] +
                              ws[b * 4 + 2] + ws[b * 4 + 3]);
    out[b] = ia / (pa + ga - ia);
  }
}

// ---------------------------------------------------------------------------
extern "C" void kernel_launch(void* const* d_in, const int* in_sizes, int n_in,
                              void* d_out, int out_size, void* d_ws, size_t ws_size,
                              hipStream_t stream) {
  const float* poly    = (const float*)d_in[0];
  const float* gt      = (const float*)d_in[1];
  const float* gt_mask = (const float*)d_in[2];
  float* out = (float*)d_out;
  float* ws  = (float*)d_ws;   // 2048 floats: |s| per (batch, direction)

  hipLaunchKernelGGL(diffiou_intersect, dim3(BS * 4), dim3(256), 0, stream,
                     poly, gt_mask, ws);
  hipLaunchKernelGGL(diffiou_finalize, dim3(BS), dim3(64), 0, stream,
                     poly, gt, ws, out);
}

// Round 15
// 32.632 us; speedup vs baseline: 1.3756x; 1.0931x over previous
//
#include <hip/hip_runtime.h>
#include <math.h>

#define DIM   100
#define NV    64
#define BS    512
#define MAXCH 1664          // 128 combos * 13 chunks max, multiple of 128
#define SMW   108           // padded mask row stride (bytes)
#define SMH   103           // padded mask rows

// ---------------------------------------------------------------------------
// R10 structure (proven best: 256 thr/block, 8 blocks/CU, 2048-block grid
// fully co-resident) + T14-style async staging: mask global loads issued in
// two 5xfloat4 register batches, each hidden under independent compute
// (batch1 under per-combo setup, batch2 under prefix-scan/scatter). Mask is
// the clamp-padded u8 103x108 layout (bilinear = 4 ds_read_u8 at immediate
// offsets, exact clip() semantics). Kept-sample direct enumeration (R7-R10):
// per combo binary-search exact last valid step T (bit-exact float exprs),
// K = cells crossed; per sample t = ceil(fmaf(kf,B,A')) + one-step fixup vs
// bit-exact floor(u(t)). Sentinel fill reduced to the <=127-entry tail after
// totalChunks is known. All numerics bit-identical to R10 (absmax 4.88e-4).
// ---------------------------------------------------------------------------
template<bool AX>
__device__ __forceinline__ float mainloop(
    const unsigned char* sm, const float4* prmA, const float4* prmB,
    const unsigned short* chunkTab, int totE, int tid) {
  const int grp = tid >> 5;                // 0..7
  const int sub = (tid >> 3) & 3;          // 0..3
  const int st  = tid & 7;                 // kept-sample index within chunk
  const int base0 = grp * 16 + sub * 4;
  float acc = 0.0f;

  for (int i = 0; i * 128 < totE; ++i) {
    const ushort4 ent = *reinterpret_cast<const ushort4*>(
        &chunkTab[i * 128 + base0]);       // one ds_read_b64 per 256 samples

    // p = {x0,y0,vx,vy}; q = {shw, Kf, B, A'}
    #define SAMPLE(e) {                                                    \
      const int c = (e) >> 4;                                              \
      const float kf = (float)((((e) & 15) << 3) | st);                    \
      const float4 p = prmA[c];                                            \
      const float4 q = prmB[c];                                            \
      const float vu = AX ? p.z : p.w;                                     \
      const float u0 = AX ? p.x : p.y;                                     \
      const float fu0 = floorf(u0);                                        \
      const float ck = fu0 + __builtin_copysignf(kf, vu);                  \
      const float te = ceilf(fmaf(kf, q.z, q.w));                          \
      const float u1 = __fadd_rn(__fmul_rn(te, vu), u0);                   \
      float t = (floorf(u1) == ck) ? te : (te + 1.0f);                     \
      t = fmaxf(t, 0.0f);                                                  \
      const float xs = __fadd_rn(__fmul_rn(t, p.z), p.x);                  \
      const float ys = __fadd_rn(__fmul_rn(t, p.w), p.y);                  \
      const float X0 = floorf(xs), Y0 = floorf(ys);                        \
      const float wx1 = xs - X0, wy1 = ys - Y0;                            \
      const float wx0 = 1.0f - wx1, wy0 = 1.0f - wy1;                      \
      const int ix = max(min((int)X0, 100), -1);                           \
      const int iy = max(min((int)Y0, 100), -1);                           \
      const int a = iy * SMW + ix;                                         \
      const float g00 = (float)sm[a + (SMW + 4)];                          \
      const float g10 = (float)sm[a + (SMW + 5)];                          \
      const float g01 = (float)sm[a + (2 * SMW + 4)];                      \
      const float g11 = (float)sm[a + (2 * SMW + 5)];                      \
      const float top = fmaf(wx1, g10, wx0 * g00);                         \
      const float bot = fmaf(wx1, g11, wx0 * g01);                         \
      const float val = fmaf(wy1, bot, wy0 * top);                         \
      const float w = (kf <= q.y) ? q.x : 0.0f;                            \
      acc = fmaf(w, val, acc);                                             \
    }
    SAMPLE(ent.x); SAMPLE(ent.y); SAMPLE(ent.z); SAMPLE(ent.w);
    #undef SAMPLE
  }
  return acc;
}

__global__ __launch_bounds__(256, 8) void diffiou_intersect(
    const float* __restrict__ poly, const float* __restrict__ gt_mask,
    float* __restrict__ ws) {
  __shared__ unsigned char sm[SMH * SMW];        // 11124 B, clamp-padded
  __shared__ float4 prmA[128];                   // 2048 B: x0,y0,vx,vy
  __shared__ float4 prmB[128];                   // 2048 B: shw,Kf,B,A'
  __shared__ unsigned short chunkTab[MAXCH];     // 3328 B
  __shared__ int   wsum[2];
  __shared__ int   totalChunks;
  __shared__ float red[4];

  const int bid = blockIdx.x;
  const int b   = bid >> 2;
  const int m   = bid & 3;
  const bool ax = (m < 2);                 // DIRECTIONS = x,x,y,y
  const int tid = threadIdx.x;

  const float*  src  = gt_mask + (size_t)(b * 4 + m) * (DIM * DIM);
  const float4* src4 = reinterpret_cast<const float4*>(src);

  // ---- issue staging batch 1 (j = tid + 256k, k = 0..4; j < 1280) ----
  float4 L0 = src4[tid];
  float4 L1 = src4[tid + 256];
  float4 L2 = src4[tid + 512];
  float4 L3 = src4[tid + 768];
  float4 L4 = src4[tid + 1024];

  // convert+write a linear float4 j -> padded row j/25 + 1, col 4 + 4*(j%25)
  #define CVTW(L, j) {                                                     \
    const int r_ = (j) / 25;                                               \
    const int g_ = (j) - r_ * 25;                                          \
    const unsigned int c0 = (unsigned int)__float2int_rn((L).x * 255.0f);  \
    const unsigned int c1 = (unsigned int)__float2int_rn((L).y * 255.0f);  \
    const unsigned int c2 = (unsigned int)__float2int_rn((L).z * 255.0f);  \
    const unsigned int c3 = (unsigned int)__float2int_rn((L).w * 255.0f);  \
    *reinterpret_cast<unsigned int*>(&sm[(r_ + 1) * SMW + 4 + 4 * g_]) =   \
        c0 | (c1 << 8) | (c2 << 16) | (c3 << 24);                          \
  }

  // ---- per-combo setup (poly only; overlaps batch-1 HBM latency) ----
  int ncv = 0;
  if (tid < 128) {
    const int e  = tid >> 1;
    const int fb = tid & 1;
    const float* pb = poly + (size_t)b * NV * 2;
    const float ex0 = pb[e * 2 + 0], ey0 = pb[e * 2 + 1];
    const int   en  = (e + 1) & (NV - 1);
    const float ex1 = pb[en * 2 + 0], ey1 = pb[en * 2 + 1];
    const float sign = (ax ? (ex1 > ex0) : (ey1 > ey0)) ? 1.0f : -1.0f;
    const float x0 = fb ? ex1 : ex0, y0 = fb ? ey1 : ey0;
    const float x1 = fb ? ex0 : ex1, y1 = fb ? ey0 : ey1;
    float vx = (x1 - x0) + 1e-6f;
    float vy = (y1 - y0) + 1e-6f;
    const float n = __fsqrt_rn(__fadd_rn(__fmul_rn(vx, vx), __fmul_rn(vy, vy)));
    vx = __fdiv_rn(vx, n);
    vy = __fdiv_rn(vy, n);
    // bbox + tolerances; u-bound [0,99] folded into the axis coord (exact)
    float xlo = fminf(x0, x1) - 0.001f, xhi = fmaxf(x0, x1) + 0.001f;
    float ylo = fminf(y0, y1) - 0.001f, yhi = fmaxf(y0, y1) + 0.001f;
    if (ax) { xlo = fmaxf(xlo, 0.0f); xhi = fminf(xhi, (float)(DIM - 1)); }
    else    { ylo = fmaxf(ylo, 0.0f); yhi = fminf(yhi, (float)(DIM - 1)); }

    #define VALID_AT(tt, out_) {                                  \
      const float tf_ = (float)(tt);                              \
      const float xs_ = __fadd_rn(__fmul_rn(tf_, vx), x0);        \
      const float ys_ = __fadd_rn(__fmul_rn(tf_, vy), y0);        \
      out_ = (xs_ <= xhi) && (xs_ >= xlo) &&                      \
             (ys_ <= yhi) && (ys_ >= ylo);                        \
    }
    int T;
    bool v200; VALID_AT(200, v200);
    if (v200) { T = 200; }
    else {
      int lo = 0, hi = 200;
      #pragma unroll
      for (int it = 0; it < 8; ++it) {
        const int mid = (lo + hi) >> 1;
        bool vm; VALID_AT(mid, vm);
        if (vm) lo = mid; else hi = mid;
      }
      T = lo;
    }
    #undef VALID_AT

    const float vu  = ax ? vx : vy;
    const float u0  = ax ? x0 : y0;
    const float fu0 = floorf(u0);
    const float uT  = __fadd_rn(__fmul_rn((float)T, vu), u0);
    int K = abs((int)floorf(uT) - (int)fu0);
    K = min(K, 99);
    const float B = __fdiv_rn(1.0f, fabsf(vu));
    const float D = (vu > 0.0f) ? (fu0 - u0) : (u0 - fu0 - 1.0f);
    prmA[tid] = make_float4(x0, y0, vx, vy);
    prmB[tid] = make_float4(sign * (0.5f / 255.0f), (float)K,
                            B, fmaf(D, B, -0.005f));
    ncv = (K >> 3) + 1;                    // 8-kept chunks, <= 13
  }

  // ---- write batch 1, issue batch 2 (j = tid + 1280 + 256k, k = 0..4) ----
  CVTW(L0, tid);
  CVTW(L1, tid + 256);
  CVTW(L2, tid + 512);
  CVTW(L3, tid + 768);
  CVTW(L4, tid + 1024);
  const int j5 = tid + 1280, j6 = tid + 1536, j7 = tid + 1792,
            j8 = tid + 2048, j9 = tid + 2304;
  L0 = src4[j5];
  L1 = src4[j6];
  L2 = src4[j7];
  L3 = src4[j8];
  L4 = (j9 < 2500) ? src4[j9] : make_float4(0.f, 0.f, 0.f, 0.f);

  // ---- prefix scan (waves 0-1; overlaps batch-2 HBM latency) ----
  int v = ncv;
  #pragma unroll
  for (int i = 1; i < 64; i <<= 1) {
    const int w = __shfl_up(v, i, 64);
    if ((tid & 63) >= i) v += w;
  }
  if (((tid & 63) == 63) && (tid < 128)) wsum[tid >> 6] = v;
  __syncthreads();
  if ((tid >= 64) && (tid < 128)) v += wsum[0];
  if (tid < 128) {
    const int start = v - ncv;
    for (int k = 0; k < ncv; ++k)
      chunkTab[start + k] = (unsigned short)((tid << 4) | k);
    if (tid == 127) totalChunks = v;
  }

  // ---- write batch 2 + duplicated rows + border cols ----
  CVTW(L0, j5);
  CVTW(L1, j6);
  CVTW(L2, j7);
  CVTW(L3, j8);
  if (j9 < 2500) CVTW(L4, j9);
  if (tid < 75) {                          // dst rows 0, 101, 102
    const int rr = tid / 25;               // 0..2
    const int g  = tid - rr * 25;
    const int srow = (rr == 0) ? 0 : (DIM - 1);
    const int drow = (rr == 0) ? 0 : (100 + rr);
    const float4 q = src4[srow * 25 + g];
    const unsigned int c0 = (unsigned int)__float2int_rn(q.x * 255.0f);
    const unsigned int c1 = (unsigned int)__float2int_rn(q.y * 255.0f);
    const unsigned int c2 = (unsigned int)__float2int_rn(q.z * 255.0f);
    const unsigned int c3 = (unsigned int)__float2int_rn(q.w * 255.0f);
    *reinterpret_cast<unsigned int*>(&sm[drow * SMW + 4 + 4 * g]) =
        c0 | (c1 << 8) | (c2 << 16) | (c3 << 24);
  }
  if (tid < SMH) {                         // border col duplicates
    const int sr = min(max(tid - 1, 0), DIM - 1);
    const unsigned char e0 =
        (unsigned char)__float2int_rn(src[sr * DIM + 0] * 255.0f);
    const unsigned char e9 =
        (unsigned char)__float2int_rn(src[sr * DIM + DIM - 1] * 255.0f);
    sm[tid * SMW + 3] = e0;
    sm[tid * SMW + 104] = e9;
    sm[tid * SMW + 105] = e9;
  }
  #undef CVTW
  __syncthreads();

  // ---- sentinel fill: only the tail up to the next multiple of 128 ----
  const int totE = totalChunks;
  const int endE = (totE + 127) & ~127;
  if (totE + tid < endE) chunkTab[totE + tid] = 15;  // c=0,k=15 -> weight 0
  __syncthreads();

  const float acc = ax ? mainloop<true >(sm, prmA, prmB, chunkTab, totE, tid)
                       : mainloop<false>(sm, prmA, prmB, chunkTab, totE, tid);

  // ---- block reduce (4 waves) ----
  float a = acc;
  #pragma unroll
  for (int o = 32; o > 0; o >>= 1) a += __shfl_xor(a, o, 64);
  if ((tid & 63) == 0) red[tid >> 6] = a;
  __syncthreads();
  if (tid == 0) {
    const float s = red[0] + red[1] + red[2] + red[3];
    ws[bid] = fabsf(s);
  }
}

// ---------------------------------------------------------------------------
// Kernel 2: per-batch areas + final IoU. One wave per batch.
// ---------------------------------------------------------------------------
__device__ __forceinline__ float wave_area(const float* P, int b, int v) {
  const float x0 = P[(size_t)(b * NV + v) * 2 + 0];
  const float y0 = P[(size_t)(b * NV + v) * 2 + 1];
  const int vn = (v + 1) & (NV - 1);
  const float x1 = P[(size_t)(b * NV + vn) * 2 + 0];
  const float y1 = P[(size_t)(b * NV + vn) * 2 + 1];
  float ym = y0;
  #pragma unroll
  for (int o = 32; o > 0; o >>= 1) ym = fmaxf(ym, __shfl_xor(ym, o, 64));
  float term = (x1 - x0) * (ym - (y1 + y0) * 0.5f);
  #pragma unroll
  for (int o = 32; o > 0; o >>= 1) term += __shfl_xor(term, o, 64);
  return fabsf(term);
}

__global__ __launch_bounds__(64) void diffiou_finalize(
    const float* __restrict__ poly, const float* __restrict__ gt,
    const float* __restrict__ ws, float* __restrict__ out) {
  const int b = blockIdx.x;
  const int v = threadIdx.x;
  const float pa = wave_area(poly, b, v);
  const float ga = wave_area(gt, b, v);
  if (v == 0) {
    const float ia = 0.25f * (ws[b * 4 + 0] + ws[b * 4 + 1] +
                              ws[b * 4 + 2] + ws[b * 4 + 3]);
    out[b] = ia / (pa + ga - ia);
  }
}

// ---------------------------------------------------------------------------
extern "C" void kernel_launch(void* const* d_in, const int* in_sizes, int n_in,
                              void* d_out, int out_size, void* d_ws, size_t ws_size,
                              hipStream_t stream) {
  const float* poly    = (const float*)d_in[0];
  const float* gt      = (const float*)d_in[1];
  const float* gt_mask = (const float*)d_in[2];
  float* out = (float*)d_out;
  float* ws  = (float*)d_ws;   // 2048 floats: |s| per (batch, direction)

  hipLaunchKernelGGL(diffiou_intersect, dim3(BS * 4), dim3(256), 0, stream,
                     poly, gt_mask, ws);
  hipLaunchKernelGGL(diffiou_finalize, dim3(BS), dim3(64), 0, stream,
                     poly, gt, ws, out);
}

// Round 16
// 30.833 us; speedup vs baseline: 1.4558x; 1.0583x over previous
//
#include <hip/hip_runtime.h>
#include <math.h>

#define DIM   100
#define NV    64
#define BS    512
#define MAXCH 1664          // 128 combos * 13 chunks max, multiple of 128
#define SMW   108           // padded mask row stride (bytes)
#define SMH   103           // padded mask rows

// ---------------------------------------------------------------------------
// R15 structure (256 thr/block, 8 blocks/CU, async 2-batch staging, kept-
// sample direct enumeration, clamp-padded u8 mask, bilinear = 4 ds_read_u8
// at immediate offsets) + BANK-CONFLICT FIX: for AX blocks (u = x), the 8
// lanes of a chunk sample 8 byte-adjacent texels in a y-major layout ->
// 3-4-way LDS conflict on every gather. Fix: AX blocks store the mask
// TRANSPOSED (x-major). Layout rows index P (= y for AY, x for AX), byte
// cols index Q; lane-adjacent samples then step P (stride 108, 27 dwords,
// gcd(27,32)=1 -> all banks distinct) for BOTH directions. Gather = same 4
// immediate offsets; bilinear weights relabelled (wq = Q-adjacent weight).
// All rounding-sensitive math bit-identical to R15 (absmax 4.882812e-4).
// ---------------------------------------------------------------------------
template<bool AX>
__device__ __forceinline__ float mainloop(
    const unsigned char* sm, const float4* prmA, const float4* prmB,
    const unsigned short* chunkTab, int totE, int tid) {
  const int grp = tid >> 5;                // 0..7
  const int sub = (tid >> 3) & 3;          // 0..3
  const int st  = tid & 7;                 // kept-sample index within chunk
  const int base0 = grp * 16 + sub * 4;
  float acc = 0.0f;

  for (int i = 0; i * 128 < totE; ++i) {
    const ushort4 ent = *reinterpret_cast<const ushort4*>(
        &chunkTab[i * 128 + base0]);       // one ds_read_b64 per 256 samples

    // p = {x0,y0,vx,vy}; q = {shw, Kf, B, A'}
    #define SAMPLE(e) {                                                    \
      const int c = (e) >> 4;                                              \
      const float kf = (float)((((e) & 15) << 3) | st);                    \
      const float4 p = prmA[c];                                            \
      const float4 q = prmB[c];                                            \
      const float vu = AX ? p.z : p.w;                                     \
      const float u0 = AX ? p.x : p.y;                                     \
      const float fu0 = floorf(u0);                                        \
      const float ck = fu0 + __builtin_copysignf(kf, vu);                  \
      const float te = ceilf(fmaf(kf, q.z, q.w));                          \
      const float u1 = __fadd_rn(__fmul_rn(te, vu), u0);                   \
      float t = (floorf(u1) == ck) ? te : (te + 1.0f);                     \
      t = fmaxf(t, 0.0f);                                                  \
      const float xs = __fadd_rn(__fmul_rn(t, p.z), p.x);                  \
      const float ys = __fadd_rn(__fmul_rn(t, p.w), p.y);                  \
      const float X0 = floorf(xs), Y0 = floorf(ys);                        \
      const float wx1 = xs - X0, wy1 = ys - Y0;                            \
      const int ix = max(min((int)X0, 100), -1);                           \
      const int iy = max(min((int)Y0, 100), -1);                           \
      const int P = AX ? ix : iy;          /* layout row coord */          \
      const int Q = AX ? iy : ix;          /* layout byte coord */         \
      const float wq1 = AX ? wy1 : wx1;    /* Q-adjacent weight */         \
      const float wp1 = AX ? wx1 : wy1;                                    \
      const float wq0 = 1.0f - wq1, wp0 = 1.0f - wp1;                      \
      const int a = P * SMW + Q;                                           \
      const float g00 = (float)sm[a + (SMW + 4)];      /* (P  ,Q  ) */     \
      const float gq1 = (float)sm[a + (SMW + 5)];      /* (P  ,Q+1) */     \
      const float gp1 = (float)sm[a + (2 * SMW + 4)];  /* (P+1,Q  ) */     \
      const float gpq = (float)sm[a + (2 * SMW + 5)];  /* (P+1,Q+1) */     \
      const float top = fmaf(wq1, gq1, wq0 * g00);                         \
      const float bot = fmaf(wq1, gpq, wq0 * gp1);                         \
      const float val = fmaf(wp1, bot, wp0 * top);                         \
      const float w = (kf <= q.y) ? q.x : 0.0f;                           \
      acc = fmaf(w, val, acc);                                             \
    }
    SAMPLE(ent.x); SAMPLE(ent.y); SAMPLE(ent.z); SAMPLE(ent.w);
    #undef SAMPLE
  }
  return acc;
}

__global__ __launch_bounds__(256, 8) void diffiou_intersect(
    const float* __restrict__ poly, const float* __restrict__ gt_mask,
    float* __restrict__ ws) {
  __shared__ unsigned char sm[SMH * SMW];        // 11124 B, clamp-padded
  __shared__ float4 prmA[128];                   // 2048 B: x0,y0,vx,vy
  __shared__ float4 prmB[128];                   // 2048 B: shw,Kf,B,A'
  __shared__ unsigned short chunkTab[MAXCH];     // 3328 B
  __shared__ int   wsum[2];
  __shared__ int   totalChunks;
  __shared__ float red[4];

  const int bid = blockIdx.x;
  const int b   = bid >> 2;
  const int m   = bid & 3;
  const bool ax = (m < 2);                 // DIRECTIONS = x,x,y,y
  const int tid = threadIdx.x;

  const float*  src  = gt_mask + (size_t)(b * 4 + m) * (DIM * DIM);
  const float4* src4 = reinterpret_cast<const float4*>(src);

  // AY: linear float4 item j -> layout row j/25 + 1, bytes 4+4*(j%25)
  #define CVTW(L, j) {                                                     \
    const int r_ = (j) / 25;                                               \
    const int g_ = (j) - r_ * 25;                                          \
    const unsigned int c0 = (unsigned int)__float2int_rn((L).x * 255.0f);  \
    const unsigned int c1 = (unsigned int)__float2int_rn((L).y * 255.0f);  \
    const unsigned int c2 = (unsigned int)__float2int_rn((L).z * 255.0f);  \
    const unsigned int c3 = (unsigned int)__float2int_rn((L).w * 255.0f);  \
    *reinterpret_cast<unsigned int*>(&sm[(r_ + 1) * SMW + 4 + 4 * g_]) =   \
        c0 | (c1 << 8) | (c2 << 16) | (c3 << 24);                          \
  }
  // AX (transposed): item j -> (r = j%103, g = j/103); row r (x=clamp(r-1)),
  // bytes 4+4g..7+4g hold y = 4g..4g+3. Loads are 4 coalesced streams.
  #define LOADT(F, j) {                                                    \
    const int g_ = (j) / 103;                                              \
    const int r_ = (j) - g_ * 103;                                         \
    const int xx = min(max(r_ - 1, 0), DIM - 1);                           \
    (F).x = src[(4 * g_ + 0) * DIM + xx];                                  \
    (F).y = src[(4 * g_ + 1) * DIM + xx];                                  \
    (F).z = src[(4 * g_ + 2) * DIM + xx];                                  \
    (F).w = src[(4 * g_ + 3) * DIM + xx];                                  \
  }
  #define CVTWT(F, j) {                                                    \
    const int g_ = (j) / 103;                                              \
    const int r_ = (j) - g_ * 103;                                         \
    const unsigned int c0 = (unsigned int)__float2int_rn((F).x * 255.0f);  \
    const unsigned int c1 = (unsigned int)__float2int_rn((F).y * 255.0f);  \
    const unsigned int c2 = (unsigned int)__float2int_rn((F).z * 255.0f);  \
    const unsigned int c3 = (unsigned int)__float2int_rn((F).w * 255.0f);  \
    *reinterpret_cast<unsigned int*>(&sm[r_ * SMW + 4 + 4 * g_]) =         \
        c0 | (c1 << 8) | (c2 << 16) | (c3 << 24);                          \
  }

  // ---- issue staging batch 1 ----
  float4 L0, L1, L2, L3, L4;
  if (ax) {
    LOADT(L0, tid);        LOADT(L1, tid + 256);  LOADT(L2, tid + 512);
    LOADT(L3, tid + 768);  LOADT(L4, tid + 1024);
  } else {
    L0 = src4[tid];        L1 = src4[tid + 256];  L2 = src4[tid + 512];
    L3 = src4[tid + 768];  L4 = src4[tid + 1024];
  }

  // ---- per-combo setup (poly only; overlaps batch-1 HBM latency) ----
  int ncv = 0;
  if (tid < 128) {
    const int e  = tid >> 1;
    const int fb = tid & 1;
    const float* pb = poly + (size_t)b * NV * 2;
    const float ex0 = pb[e * 2 + 0], ey0 = pb[e * 2 + 1];
    const int   en  = (e + 1) & (NV - 1);
    const float ex1 = pb[en * 2 + 0], ey1 = pb[en * 2 + 1];
    const float sign = (ax ? (ex1 > ex0) : (ey1 > ey0)) ? 1.0f : -1.0f;
    const float x0 = fb ? ex1 : ex0, y0 = fb ? ey1 : ey0;
    const float x1 = fb ? ex0 : ex1, y1 = fb ? ey0 : ey1;
    float vx = (x1 - x0) + 1e-6f;
    float vy = (y1 - y0) + 1e-6f;
    const float n = __fsqrt_rn(__fadd_rn(__fmul_rn(vx, vx), __fmul_rn(vy, vy)));
    vx = __fdiv_rn(vx, n);
    vy = __fdiv_rn(vy, n);
    float xlo = fminf(x0, x1) - 0.001f, xhi = fmaxf(x0, x1) + 0.001f;
    float ylo = fminf(y0, y1) - 0.001f, yhi = fmaxf(y0, y1) + 0.001f;
    if (ax) { xlo = fmaxf(xlo, 0.0f); xhi = fminf(xhi, (float)(DIM - 1)); }
    else    { ylo = fmaxf(ylo, 0.0f); yhi = fminf(yhi, (float)(DIM - 1)); }

    #define VALID_AT(tt, out_) {                                  \
      const float tf_ = (float)(tt);                              \
      const float xs_ = __fadd_rn(__fmul_rn(tf_, vx), x0);        \
      const float ys_ = __fadd_rn(__fmul_rn(tf_, vy), y0);        \
      out_ = (xs_ <= xhi) && (xs_ >= xlo) &&                      \
             (ys_ <= yhi) && (ys_ >= ylo);                        \
    }
    int T;
    bool v200; VALID_AT(200, v200);
    if (v200) { T = 200; }
    else {
      int lo = 0, hi = 200;
      #pragma unroll
      for (int it = 0; it < 8; ++it) {
        const int mid = (lo + hi) >> 1;
        bool vm; VALID_AT(mid, vm);
        if (vm) lo = mid; else hi = mid;
      }
      T = lo;
    }
    #undef VALID_AT

    const float vu  = ax ? vx : vy;
    const float u0  = ax ? x0 : y0;
    const float fu0 = floorf(u0);
    const float uT  = __fadd_rn(__fmul_rn((float)T, vu), u0);
    int K = abs((int)floorf(uT) - (int)fu0);
    K = min(K, 99);
    const float B = __fdiv_rn(1.0f, fabsf(vu));
    const float D = (vu > 0.0f) ? (fu0 - u0) : (u0 - fu0 - 1.0f);
    prmA[tid] = make_float4(x0, y0, vx, vy);
    prmB[tid] = make_float4(sign * (0.5f / 255.0f), (float)K,
                            B, fmaf(D, B, -0.005f));
    ncv = (K >> 3) + 1;                    // 8-kept chunks, <= 13
  }

  // ---- write batch 1, issue batch 2 ----
  const int j5 = tid + 1280, j6 = tid + 1536, j7 = tid + 1792,
            j8 = tid + 2048, j9 = tid + 2304;
  if (ax) {
    CVTWT(L0, tid);        CVTWT(L1, tid + 256);  CVTWT(L2, tid + 512);
    CVTWT(L3, tid + 768);  CVTWT(L4, tid + 1024);
    LOADT(L0, j5); LOADT(L1, j6); LOADT(L2, j7); LOADT(L3, j8);
    if (j9 < 2575) LOADT(L4, j9);          // items: 103*25 = 2575
  } else {
    CVTW(L0, tid);         CVTW(L1, tid + 256);   CVTW(L2, tid + 512);
    CVTW(L3, tid + 768);   CVTW(L4, tid + 1024);
    L0 = src4[j5]; L1 = src4[j6]; L2 = src4[j7]; L3 = src4[j8];
    if (j9 < 2500) L4 = src4[j9];
  }

  // ---- prefix scan (waves 0-1; overlaps batch-2 HBM latency) ----
  int v = ncv;
  #pragma unroll
  for (int i = 1; i < 64; i <<= 1) {
    const int w = __shfl_up(v, i, 64);
    if ((tid & 63) >= i) v += w;
  }
  if (((tid & 63) == 63) && (tid < 128)) wsum[tid >> 6] = v;
  __syncthreads();
  if ((tid >= 64) && (tid < 128)) v += wsum[0];
  if (tid < 128) {
    const int start = v - ncv;
    for (int k = 0; k < ncv; ++k)
      chunkTab[start + k] = (unsigned short)((tid << 4) | k);
    if (tid == 127) totalChunks = v;
  }

  // ---- write batch 2 + borders ----
  if (ax) {
    CVTWT(L0, j5); CVTWT(L1, j6); CVTWT(L2, j7); CVTWT(L3, j8);
    if (j9 < 2575) CVTWT(L4, j9);
    if (tid < SMH) {                       // Q-border cols: y=0 and y=99 dups
      const int xx = min(max(tid - 1, 0), DIM - 1);
      const unsigned char e0 =
          (unsigned char)__float2int_rn(src[0 * DIM + xx] * 255.0f);
      const unsigned char e9 =
          (unsigned char)__float2int_rn(src[(DIM - 1) * DIM + xx] * 255.0f);
      sm[tid * SMW + 3] = e0;
      sm[tid * SMW + 104] = e9;
      sm[tid * SMW + 105] = e9;
    }
  } else {
    CVTW(L0, j5); CVTW(L1, j6); CVTW(L2, j7); CVTW(L3, j8);
    if (j9 < 2500) CVTW(L4, j9);
    if (tid < 75) {                        // dst rows 0, 101, 102
      const int rr = tid / 25;             // 0..2
      const int g  = tid - rr * 25;
      const int srow = (rr == 0) ? 0 : (DIM - 1);
      const int drow = (rr == 0) ? 0 : (100 + rr);
      const float4 q = src4[srow * 25 + g];
      const unsigned int c0 = (unsigned int)__float2int_rn(q.x * 255.0f);
      const unsigned int c1 = (unsigned int)__float2int_rn(q.y * 255.0f);
      const unsigned int c2 = (unsigned int)__float2int_rn(q.z * 255.0f);
      const unsigned int c3 = (unsigned int)__float2int_rn(q.w * 255.0f);
      *reinterpret_cast<unsigned int*>(&sm[drow * SMW + 4 + 4 * g]) =
          c0 | (c1 << 8) | (c2 << 16) | (c3 << 24);
    }
    if (tid < SMH) {                       // Q-border cols: x=0 and x=99 dups
      const int sr = min(max(tid - 1, 0), DIM - 1);
      const unsigned char e0 =
          (unsigned char)__float2int_rn(src[sr * DIM + 0] * 255.0f);
      const unsigned char e9 =
          (unsigned char)__float2int_rn(src[sr * DIM + DIM - 1] * 255.0f);
      sm[tid * SMW + 3] = e0;
      sm[tid * SMW + 104] = e9;
      sm[tid * SMW + 105] = e9;
    }
  }
  #undef CVTW
  #undef CVTWT
  #undef LOADT
  __syncthreads();

  // ---- sentinel fill: only the tail up to the next multiple of 128 ----
  const int totE = totalChunks;
  const int endE = (totE + 127) & ~127;
  if (totE + tid < endE) chunkTab[totE + tid] = 15;  // c=0,k=15 -> weight 0
  __syncthreads();

  const float acc = ax ? mainloop<true >(sm, prmA, prmB, chunkTab, totE, tid)
                       : mainloop<false>(sm, prmA, prmB, chunkTab, totE, tid);

  // ---- block reduce (4 waves) ----
  float a = acc;
  #pragma unroll
  for (int o = 32; o > 0; o >>= 1) a += __shfl_xor(a, o, 64);
  if ((tid & 63) == 0) red[tid >> 6] = a;
  __syncthreads();
  if (tid == 0) {
    const float s = red[0] + red[1] + red[2] + red[3];
    ws[bid] = fabsf(s);
  }
}

// ---------------------------------------------------------------------------
// Kernel 2: per-batch areas + final IoU. One wave per batch.
// ---------------------------------------------------------------------------
__device__ __forceinline__ float wave_area(const float* P, int b, int v) {
  const float x0 = P[(size_t)(b * NV + v) * 2 + 0];
  const float y0 = P[(size_t)(b * NV + v) * 2 + 1];
  const int vn = (v + 1) & (NV - 1);
  const float x1 = P[(size_t)(b * NV + vn) * 2 + 0];
  const float y1 = P[(size_t)(b * NV + vn) * 2 + 1];
  float ym = y0;
  #pragma unroll
  for (int o = 32; o > 0; o >>= 1) ym = fmaxf(ym, __shfl_xor(ym, o, 64));
  float term = (x1 - x0) * (ym - (y1 + y0) * 0.5f);
  #pragma unroll
  for (int o = 32; o > 0; o >>= 1) term += __shfl_xor(term, o, 64);
  return fabsf(term);
}

__global__ __launch_bounds__(64) void diffiou_finalize(
    const float* __restrict__ poly, const float* __restrict__ gt,
    const float* __restrict__ ws, float* __restrict__ out) {
  const int b = blockIdx.x;
  const int v = threadIdx.x;
  const float pa = wave_area(poly, b, v);
  const float ga = wave_area(gt, b, v);
  if (v == 0) {
    const float ia = 0.25f * (ws[b * 4 + 0] + ws[b * 4 + 1] +
                              ws[b * 4 + 2] + ws[b * 4 + 3]);
    out[b] = ia / (pa + ga - ia);
  }
}

// ---------------------------------------------------------------------------
extern "C" void kernel_launch(void* const* d_in, const int* in_sizes, int n_in,
                              void* d_out, int out_size, void* d_ws, size_t ws_size,
                              hipStream_t stream) {
  const float* poly    = (const float*)d_in[0];
  const float* gt      = (const float*)d_in[1];
  const float* gt_mask = (const float*)d_in[2];
  float* out = (float*)d_out;
  float* ws  = (float*)d_ws;   // 2048 floats: |s| per (batch, direction)

  hipLaunchKernelGGL(diffiou_intersect, dim3(BS * 4), dim3(256), 0, stream,
                     poly, gt_mask, ws);
  hipLaunchKernelGGL(diffiou_finalize, dim3(BS), dim3(64), 0, stream,
                     poly, gt, ws, out);
}